// Round 13
// baseline (220.202 us; speedup 1.0000x reference)
//
#include <hip/hip_runtime.h>
#include <hip/hip_bf16.h>
#include <math.h>

#define BB 4
#define CC 64
#define HH 128
#define WW 128
#define HW (HH*WW)          // 16384
#define NPIX (BB*HW)        // 65536

typedef __attribute__((ext_vector_type(8))) short short8;   // 8 bf16
typedef __attribute__((ext_vector_type(4))) float f32x4;

__device__ __forceinline__ float bf2f(ushort u) {
  union { unsigned u; float f; } v; v.u = ((unsigned)u) << 16; return v.f;
}
__device__ __forceinline__ ushort f2bf(float f) {
  __hip_bfloat16 h = __float2bfloat16(f); return *(ushort*)&h;
}

// ---------------------------------------------------------------------------
// Prep (verified, unchanged): NCHW fp32 -> channels-last bf16 + weights.
// ---------------------------------------------------------------------------
__global__ __launch_bounds__(256) void k_prep(
    const float* __restrict__ x, const float* __restrict__ inter,
    const float* __restrict__ w_off, const float* __restrict__ w_dcn,
    const float* __restrict__ wg1, const float* __restrict__ wb1,
    const float* __restrict__ wg2, const float* __restrict__ wb2,
    ushort* __restrict__ x_clh, ushort* __restrict__ inter_clh,
    ushort* __restrict__ wfb, ushort* __restrict__ wdT,
    ushort* __restrict__ w1gb, ushort* __restrict__ w1bb,
    ushort* __restrict__ w2gb, ushort* __restrict__ w2bb,
    float* __restrict__ zp) {
  __shared__ __align__(16) float tile[64 * 128];   // 32 KiB, xor-swizzled
  int blk = blockIdx.x;
  int tid = threadIdx.x;
  if (blk < 1024) {
    int sel = blk >> 9;
    int bh = blk & 511;
    int b = bh >> 7, h = bh & 127;
    const float* src = sel ? inter : x;
    ushort* dst = sel ? inter_clh : x_clh;
    const float* sp = src + (size_t)(b * 64) * HW + h * WW;
#pragma unroll
    for (int it = 0; it < 8; ++it) {
      int idx = it * 256 + tid;
      int c = idx >> 5, wq = idx & 31;
      float4 v = *(const float4*)(sp + (size_t)c * HW + wq * 4);
      int s = (c >> 3) & 7;
      *(float4*)(&tile[c * 128 + ((wq ^ s) << 2)]) = v;
    }
    __syncthreads();
    ushort* dp = dst + ((size_t)b * HW + h * WW) * 64;
#pragma unroll
    for (int it = 0; it < 4; ++it) {
      int idx = it * 256 + tid;
      int w = idx >> 3, c8 = idx & 7;
      short8 outv;
#pragma unroll
      for (int j = 0; j < 8; ++j) {
        int c = c8 * 8 + j;
        int sl = (w >> 2) ^ c8;
        float f = tile[c * 128 + (sl << 2) + (w & 3)];
        outv[j] = (short)f2bf(f);
      }
      *(short8*)(dp + (size_t)w * 64 + c8 * 8) = outv;
    }
  } else if (blk < 1168) {
    int i = (blk - 1024) * 256 + tid;
    if (i < 64) zp[i] = 0.f;
    if (i < 9 * 32 * 128) {
      int tap = i >> 12, rem = i & 4095, m = rem >> 7, c = rem & 127;
      float v = (m < 27) ? w_off[(size_t)(m * 128 + c) * 9 + tap] : 0.f;
      wfb[i] = f2bf(v);
    }
  } else if (blk < 1312) {
    int i = (blk - 1168) * 256 + tid;
    if (i < 64 * 64 * 9) {
      int o = i / 576, rem = i % 576, k = rem >> 6, c = rem & 63;
      wdT[i] = f2bf(w_dcn[(o * 64 + c) * 9 + k]);
    }
  } else {
    int i = (blk - 1312) * 256 + tid;   // 0..16383
    int m = i >> 12, j = i & 4095;
    const float* src = (m == 0) ? wg1 : (m == 1) ? wb1 : (m == 2) ? wg2 : wb2;
    ushort* dst = (m == 0) ? w1gb : (m == 1) ? w1bb : (m == 2) ? w2gb : w2bb;
    dst[j] = f2bf(src[j]);
  }
}

// ---------------------------------------------------------------------------
// OMEGA v13 = v12 (best: 80.4 us) at 512 THREADS: same NPX=64, same 11-barrier
// schedule, same LDS map — per-THREAD work halved (W is serial-latency-bound
// at VALUBusy 29%; halving the per-thread chain should shrink the block
// critical path toward S + W/2).
//  8 waves: conv wave=(pt 0-3, mt 0-1) 16px x 16m; SFT wave=(ph, og);
//  DCN: gather 2304 tasks over 512 thr (16B/lane), MFMA 18/half/wave.
// No launch_bounds clamp (spill tripwire = WRITE_SIZE must stay 16384 KB).
// LDS alias map (48896 B total; serial reuse, barrier-separated):
//   [0,28512)      conv passes: halo 3 rows x 66 px x 72 shorts (x, then i)
//   [0,9216)       ph3-4: Sg 64px x 72 | [9216,18432): Sb
//   [18432,25560)  post-conv..ph5: oml 27 x 66 f32
//   [0,11520)      ph5-6: coords cy/cx/cwy/cwx/cm (5 x 576 x 4 B)
//   [11520,48896)  ph6: S 32 px x 584 shorts (overlays dead oml)
// ---------------------------------------------------------------------------
#define NPX 64
#define FPX 72       // Sg/Sb short pitch per pixel
#define SP2 584      // S short pitch per pixel (576 + 8 pad)

__global__ __launch_bounds__(512) void k_omega(
    const float* __restrict__ x, const ushort* __restrict__ x_clh,
    const ushort* __restrict__ inter_clh,
    const float* __restrict__ b_off, const ushort* __restrict__ wfb,
    const ushort* __restrict__ wdT,
    const ushort* __restrict__ w1gb, const ushort* __restrict__ w1bb,
    const ushort* __restrict__ w2gb, const ushort* __restrict__ w2bb,
    const ushort* __restrict__ zp16, float* __restrict__ out) {
  __shared__ __align__(16) ushort LDSB[24448];           // 48896 B
  ushort* halo = LDSB;                    // conv passes [0,28512)
  ushort* Sg = LDSB;                      // [0,9216)
  ushort* Sb = LDSB + 4608;               // [9216,18432)
  float* oml = (float*)(LDSB + 9216);     // byte 18432: 27 x 66 f32
  int*   cy  = (int*)LDSB;                // coords [0,11520)
  int*   cx  = cy + 576;
  float* cwy = (float*)(cx + 576);
  float* cwx = cwy + 576;
  float* cm  = cwx + 576;
  ushort* S  = LDSB + 5760;               // byte 11520: 32 x 584 shorts

  int tid = threadIdx.x;
  int wave = tid >> 6, lane = tid & 63;
  int quad = lane >> 4, col = lane & 15;
  // XCD-chunked swizzle (bijective: 1024 = 8 x 128).
  int bid = blockIdx.x;
  int wid = (bid & 7) * 128 + (bid >> 3);
  int pg0 = wid * NPX;
  int b = pg0 >> 14, hw0 = pg0 & 16383;
  int h = hw0 >> 7, w0 = hw0 & 127;       // w0 in {0, 64}
  int pt = wave >> 1, mt = wave & 1;      // conv roles: 16px x 16m
  int ph = wave >> 2, og = wave & 3;      // SFT/DCN roles
  int o_base = __builtin_amdgcn_readfirstlane(og * 16);

  // ---- conv: two split-halo passes (x, then inter) ----
  f32x4 accx = {0.f, 0.f, 0.f, 0.f}, acci = {0.f, 0.f, 0.f, 0.f};
  {
    int ch = (tid & 7) * 8;
    unsigned bbase = (unsigned)b * HW;
    const ushort* wb0 = wfb + (size_t)(mt * 16 + col) * 128 + quad * 8;
    int pxb = pt * 16 + col;
#pragma unroll 1
    for (int pass = 0; pass < 2; ++pass) {
      const ushort* sb = pass ? inter_clh : x_clh;
#pragma unroll
      for (int it = 0; it < 4; ++it) {
        int e = it * 64 + (tid >> 3);
        if (e < 198) {
          int row = e / 66, pxl = e % 66;
          int hs = h + row - 1;
          int ps = w0 + pxl - 1;
          bool ok = ((unsigned)hs < 128u) && ((unsigned)ps < 128u);
          int hc = hs < 0 ? 0 : (hs > 127 ? 127 : hs);
          int pc = ps < 0 ? 0 : (ps > 127 ? 127 : ps);
          short8 v = *(const short8*)(sb + ((size_t)(bbase + (hc << 7) + pc)) * 64 + ch);
          short8 z = {0, 0, 0, 0, 0, 0, 0, 0};
          if (!ok) v = z;
          *(short8*)(&halo[e * 72 + ch]) = v;
        }
      }
      __syncthreads();   // halo(pass) visible
      int aoff = pass ? 64 : 0;    // wfb c-slice: x=[0,64), inter=[64,128)
      f32x4 ap = {0.f, 0.f, 0.f, 0.f};
#pragma unroll
      for (int ky = 0; ky < 3; ++ky) {
#pragma unroll
        for (int kx = 0; kx < 3; ++kx) {
          const ushort* wt = wb0 + (size_t)(ky * 3 + kx) * 4096 + aoff;
#pragma unroll
          for (int ks = 0; ks < 2; ++ks) {
            short8 a = *(const short8*)(wt + ks * 32);
            short8 bv = *(const short8*)(&halo[(ky * 66 + pxb + kx) * 72 + ks * 32 + quad * 8]);
            ap = __builtin_amdgcn_mfma_f32_16x16x32_bf16(a, bv, ap, 0, 0, 0);
          }
        }
      }
      if (pass) acci = ap; else accx = ap;
      __syncthreads();   // halo reads done; buffer free (restage / aliases)
    }
  }

  // oml write (halo dead; oml [18432,25560) now safe; readers wait at B2)
#pragma unroll
  for (int r = 0; r < 4; ++r) {
    int o = mt * 16 + quad * 4 + r;
    if (o < 27) oml[o * 66 + pt * 16 + col] = accx[r] + acci[r];
  }

  // ---- phase 3: SFT stage A (my 16 o x my 32 px-half) -> Sg/Sb ----
  f32x4 ag[2], ab[2];
#pragma unroll
  for (int nt = 0; nt < 2; ++nt) {
    ag[nt] = (f32x4){0.f, 0.f, 0.f, 0.f};
    ab[nt] = (f32x4){0.f, 0.f, 0.f, 0.f};
  }
#pragma unroll
  for (int ks = 0; ks < 2; ++ks) {
    short8 a_g = *(const short8*)(w1gb + (size_t)(o_base + col) * 64 + ks * 32 + quad * 8);
    short8 a_b = *(const short8*)(w1bb + (size_t)(o_base + col) * 64 + ks * 32 + quad * 8);
#pragma unroll
    for (int nt = 0; nt < 2; ++nt) {
      short8 bf = *(const short8*)(inter_clh + (size_t)(pg0 + ph * 32 + nt * 16 + col) * 64 + ks * 32 + quad * 8);
      ag[nt] = __builtin_amdgcn_mfma_f32_16x16x32_bf16(a_g, bf, ag[nt], 0, 0, 0);
      ab[nt] = __builtin_amdgcn_mfma_f32_16x16x32_bf16(a_b, bf, ab[nt], 0, 0, 0);
    }
  }
#pragma unroll
  for (int nt = 0; nt < 2; ++nt) {
    int px = ph * 32 + nt * 16 + col;
    ushort pkg[4], pkb[4];
#pragma unroll
    for (int r = 0; r < 4; ++r) {
      float vg = ag[nt][r]; vg = vg >= 0.f ? vg : 0.1f * vg;
      float vb = ab[nt][r]; vb = vb >= 0.f ? vb : 0.1f * vb;
      pkg[r] = f2bf(vg); pkb[r] = f2bf(vb);
    }
    *(uint2*)(&Sg[px * FPX + o_base + quad * 4]) = *(uint2*)pkg;
    *(uint2*)(&Sb[px * FPX + o_base + quad * 4]) = *(uint2*)pkb;
  }
  __syncthreads();   // B2: oml + Sg/Sb visible

  // ---- phase 4: SFT stage B -> ev[2][4]; px mapping matches DCN (hh, ph) ----
  f32x4 gg[2], gb[2];
#pragma unroll
  for (int hh = 0; hh < 2; ++hh) {
    gg[hh] = (f32x4){0.f, 0.f, 0.f, 0.f};
    gb[hh] = (f32x4){0.f, 0.f, 0.f, 0.f};
  }
#pragma unroll
  for (int ks = 0; ks < 2; ++ks) {
    short8 a_g = *(const short8*)(w2gb + (size_t)(o_base + col) * 64 + ks * 32 + quad * 8);
    short8 a_b = *(const short8*)(w2bb + (size_t)(o_base + col) * 64 + ks * 32 + quad * 8);
#pragma unroll
    for (int hh = 0; hh < 2; ++hh) {
      int px = hh * 32 + ph * 16 + col;
      short8 bgf = *(const short8*)(Sg + (size_t)px * FPX + ks * 32 + quad * 8);
      short8 bbf = *(const short8*)(Sb + (size_t)px * FPX + ks * 32 + quad * 8);
      gg[hh] = __builtin_amdgcn_mfma_f32_16x16x32_bf16(a_g, bgf, gg[hh], 0, 0, 0);
      gb[hh] = __builtin_amdgcn_mfma_f32_16x16x32_bf16(a_b, bbf, gb[hh], 0, 0, 0);
    }
  }
  float ev[2][4];
#pragma unroll
  for (int hh = 0; hh < 2; ++hh)
#pragma unroll
    for (int r = 0; r < 4; ++r) {
      int o = o_base + quad * 4 + r;
      int px = hh * 32 + ph * 16 + col;
      float xv = x[(size_t)(b * 64 + o) * HW + hw0 + px];
      ev[hh][r] = xv + xv * gg[hh][r] + gb[hh][r];
    }
  __syncthreads();   // B3: Sg/Sb dead -> region becomes coords

  // ---- phase 5: coords (9 taps x 64 px) from oml ----
  for (int i = tid; i < 9 * NPX; i += 512) {
    int t = i >> 6, p = i & 63;
    float dy = oml[t * 66 + p] + b_off[t];
    float dx = oml[(9 + t) * 66 + p] + b_off[9 + t];
    float mz = oml[(18 + t) * 66 + p] + b_off[18 + t];
    float py = (float)(h + (t / 3) - 1) + dy;
    float px = (float)(w0 + p + (t % 3) - 1) + dx;
    float y0f = floorf(py), x0f = floorf(px);
    cy[i] = (int)y0f;
    cx[i] = (int)x0f;
    cwy[i] = py - y0f;
    cwx[i] = px - x0f;
    cm[i] = 1.f / (1.f + __expf(-mz));
  }
  __syncthreads();   // B4: coords ready; oml dead (S may overlay)

  // ---- phase 6: DCN in 2 px-halves; S holds full 576 ch-tap per px ----
  f32x4 acc[2];
  acc[0] = (f32x4){0.f, 0.f, 0.f, 0.f};
  acc[1] = (f32x4){0.f, 0.f, 0.f, 0.f};

  const ushort* bp = x_clh + (size_t)b * HW * 64;

#pragma unroll 1
  for (int half = 0; half < 2; ++half) {
    if (half) __syncthreads();   // S free (prev MFMA reads done)
    // gather: 2304 (t,p,g8) tasks over 512 threads (16B/lane loads)
#pragma unroll 1
    for (int it = 0; it < 5; ++it) {
      int tau = it * 512 + tid;
      if (tau < 2304) {
        int tp = tau >> 3, g8 = tau & 7;
        int t = tp >> 5, p = tp & 31;
        int idx = t * 64 + half * 32 + p;
        int y0 = cy[idx], x0 = cx[idx];
        float wy = cwy[idx], wx = cwx[idx], m = cm[idx];
        bool yok0 = (unsigned)y0 < 128u, yok1 = (unsigned)(y0 + 1) < 128u;
        bool xok0 = (unsigned)x0 < 128u, xok1 = (unsigned)(x0 + 1) < 128u;
        const ushort* r0 = bp + ((size_t)(int)((y0 << 7) + x0)) * 64 + g8 * 8;
        const ushort* r1 = r0 + (size_t)WW * 64;
        short8 s00 = *(const short8*)((yok0 && xok0) ? r0 : (zp16 + g8 * 8));
        short8 s01 = *(const short8*)((yok0 && xok1) ? (r0 + 64) : (zp16 + g8 * 8));
        short8 s10 = *(const short8*)((yok1 && xok0) ? r1 : (zp16 + g8 * 8));
        short8 s11 = *(const short8*)((yok1 && xok1) ? (r1 + 64) : (zp16 + g8 * 8));
        short8 outv;
#pragma unroll
        for (int j = 0; j < 8; ++j) {
          float v00 = bf2f((ushort)s00[j]), v01 = bf2f((ushort)s01[j]);
          float v10 = bf2f((ushort)s10[j]), v11 = bf2f((ushort)s11[j]);
          float top = v00 + (v01 - v00) * wx;
          float bot = v10 + (v11 - v10) * wx;
          float val = top + (bot - top) * wy;
          outv[j] = (short)f2bf(val * m);
        }
        *(short8*)(&S[p * SP2 + t * 64 + g8 * 8]) = outv;
      }
    }
    __syncthreads();   // S ready
    const ushort* wrow = wdT + (size_t)(o_base + col) * 576 + quad * 8;
    const ushort* srow = S + (size_t)(ph * 16 + col) * SP2 + quad * 8;
#pragma unroll
    for (int ks = 0; ks < 18; ++ks) {
      short8 a = *(const short8*)(wrow + ks * 32);
      short8 bfv = *(const short8*)(srow + ks * 32);
      acc[half] = __builtin_amdgcn_mfma_f32_16x16x32_bf16(a, bfv, acc[half], 0, 0, 0);
    }
  }

  // ---- phase 7: epilogue: out = ev + dcn (single pure write) ----
#pragma unroll
  for (int hh = 0; hh < 2; ++hh)
#pragma unroll
    for (int r = 0; r < 4; ++r) {
      int o = o_base + quad * 4 + r;
      int px = hh * 32 + ph * 16 + col;
      size_t idx = (size_t)(b * 64 + o) * HW + hw0 + px;
      out[idx] = ev[hh][r] + acc[hh][r];
    }
}

// ---------------------------------------------------------------------------
// Workspace plan (float slots), compacted ~17 MB (r4-verified):
//   x_clh     ushort [0        .. 2097152)
//   inter_clh ushort [2097152  .. 4194304)
//   wfb       ushort [4194304  .. 4212736)
//   wdT       ushort [4212736  .. 4231168)
//   w1gb/w1bb/w2gb/w2bb ushort 4 x 2048 float slots [4231168 .. 4239360)
//   zp        fp32   [4239360  .. 4239424)
// ---------------------------------------------------------------------------
extern "C" void kernel_launch(void* const* d_in, const int* in_sizes, int n_in,
                              void* d_out, int out_size, void* d_ws, size_t ws_size,
                              hipStream_t stream) {
  const float* x     = (const float*)d_in[0];
  const float* inter = (const float*)d_in[1];
  const float* w_off = (const float*)d_in[2];
  const float* b_off = (const float*)d_in[3];
  const float* w_dcn = (const float*)d_in[4];
  const float* wg1   = (const float*)d_in[5];
  const float* wg2   = (const float*)d_in[6];
  const float* wb1   = (const float*)d_in[7];
  const float* wb2   = (const float*)d_in[8];
  float* out = (float*)d_out;

  float* ws        = (float*)d_ws;
  ushort* x_clh    = (ushort*)ws;
  ushort* inter_clh= (ushort*)(ws + 2097152);
  ushort* wfb      = (ushort*)(ws + 4194304);
  ushort* wdT      = (ushort*)(ws + 4212736);
  ushort* w1gb     = (ushort*)(ws + 4231168);
  ushort* w1bb     = (ushort*)(ws + 4233216);
  ushort* w2gb     = (ushort*)(ws + 4235264);
  ushort* w2bb     = (ushort*)(ws + 4237312);
  float* zp        = ws + 4239360;

  // Prep: channels-last bf16 inputs + all packed weights + zero page.
  k_prep<<<1376, 256, 0, stream>>>(x, inter, w_off, w_dcn, wg1, wb1, wg2, wb2,
                                   x_clh, inter_clh, wfb, wdT,
                                   w1gb, w1bb, w2gb, w2bb, zp);

  // Fully fused conv + SFT + DCN (v13: v12 schedule at 512 threads).
  k_omega<<<1024, 512, 0, stream>>>(x, x_clh, inter_clh, b_off, wfb, wdT,
                                    w1gb, w1bb, w2gb, w2bb,
                                    (const ushort*)zp, out);
}